// Round 3
// baseline (1116.346 us; speedup 1.0000x reference)
//
#include <hip/hip_runtime.h>
#include <hip/hip_bf16.h>
#include <stdint.h>

// Int8Linear: y[m,n] = scale[n] * sum_k x[m,k]*w[n,k] + bias[n]
// DEVICE dtypes (harness maps float16 -> float32!):
//   x: float32 [M=8192, K=4096]; w: int32 [N=11008, K=4096] (|v|<=127);
//   scale: float32 [N]; bias: float32 [N]; out: float32 [M, N].
// Pre-convert W and X to bf16 in d_ws, then m97-structure 128x128 MFMA GEMM
// (global_load_lds width=16, 2-barrier K-loop, bijective XCD swizzle).

#define K_DIM 4096
#define N_DIM 11008
#define M_DIM 8192
#define BM 128
#define BN 128
#define BK 32
#define NT (N_DIM / BN)  /* 86 */
#define MT (M_DIM / BM)  /* 64 */

typedef __attribute__((ext_vector_type(8))) __bf16 bf16x8;
typedef __attribute__((ext_vector_type(4))) float f32x4;
typedef __attribute__((ext_vector_type(4))) int i32x4;

__device__ __forceinline__ void gload_lds16(const void* g, void* l) {
  __builtin_amdgcn_global_load_lds(
      (const __attribute__((address_space(1))) void*)g,
      (__attribute__((address_space(3))) void*)l, 16, 0, 0);
}

// int32 -> bf16 (exact for |v| <= 127), 8 elems/thread.
__global__ void __launch_bounds__(256) wconv_kernel(const int* __restrict__ w,
                                                    __bf16* __restrict__ o,
                                                    int n8) {
  int i = blockIdx.x * 256 + threadIdx.x;
  if (i >= n8) return;
  const i32x4* src = (const i32x4*)w;
  i32x4 v0 = src[2 * i];
  i32x4 v1 = src[2 * i + 1];
  bf16x8 r;
#pragma unroll
  for (int j = 0; j < 4; ++j) {
    r[j]     = (__bf16)(float)v0[j];
    r[j + 4] = (__bf16)(float)v1[j];
  }
  *((bf16x8*)o + i) = r;
}

// float32 -> bf16 (RNE), 8 elems/thread.
__global__ void __launch_bounds__(256) xconv_kernel(const float* __restrict__ x,
                                                    __bf16* __restrict__ o,
                                                    int n8) {
  int i = blockIdx.x * 256 + threadIdx.x;
  if (i >= n8) return;
  const f32x4* src = (const f32x4*)x;
  f32x4 v0 = src[2 * i];
  f32x4 v1 = src[2 * i + 1];
  bf16x8 r;
#pragma unroll
  for (int j = 0; j < 4; ++j) {
    r[j]     = (__bf16)v0[j];
    r[j + 4] = (__bf16)v1[j];
  }
  *((bf16x8*)o + i) = r;
}

__device__ __forceinline__ bf16x8 cvt8f(f32x4 a, f32x4 b) {
  bf16x8 h;
#pragma unroll
  for (int j = 0; j < 4; ++j) {
    h[j]     = (__bf16)a[j];
    h[j + 4] = (__bf16)b[j];
  }
  return h;
}

__device__ __forceinline__ bf16x8 cvt8i(i32x4 a, i32x4 b) {
  bf16x8 h;
#pragma unroll
  for (int j = 0; j < 4; ++j) {
    h[j]     = (__bf16)(float)a[j];
    h[j + 4] = (__bf16)(float)b[j];
  }
  return h;
}

// MODE 0: X and W preconverted (gload_lds both).
// MODE 1: W preconverted (gload_lds); X staged from fp32 via registers.
// MODE 2: no workspace; both staged via registers with conversion.
template <int MODE>
__global__ void __launch_bounds__(256, 2) gemm_kernel(
    const float* __restrict__ X,
    const __bf16* __restrict__ Xb,
    const __bf16* __restrict__ Wb,
    const int* __restrict__ Wq,
    const float* __restrict__ scale,
    const float* __restrict__ bias,
    float* __restrict__ out) {
  __shared__ __align__(16) __bf16 As[BM * BK];
  __shared__ __align__(16) __bf16 Bs[BN * BK];

  const int tid = threadIdx.x;
  const int lane = tid & 63;
  const int wv = tid >> 6;

  // bijective XCD swizzle: 5504 blocks = 8 * 688
  const int lid = blockIdx.x;
  const int swz = (lid & 7) * ((MT * NT) >> 3) + (lid >> 3);
  const int tm = swz / NT;
  const int tn = swz - tm * NT;
  const int m0 = tm * BM;
  const int n0 = tn * BN;

  // tile = 128x32 = 4096 elems; thread owns 8 elems at e0 and 8 at e1.
  // elem e -> row e>>5, col e&31 (row-major [128][32]).
  const int e0 = wv * 512 + lane * 8;
  const int e1 = e0 + 2048;
  const int r0 = e0 >> 5, c0 = e0 & 31;
  const int r1 = e1 >> 5, c1 = e1 & 31;

  f32x4 acc[4][4];
#pragma unroll
  for (int m = 0; m < 4; ++m)
#pragma unroll
    for (int n = 0; n < 4; ++n) acc[m][n] = (f32x4){0.f, 0.f, 0.f, 0.f};

  const int wm = (wv >> 1) * 64;  // wave 2x2 over 128x128 -> 64x64 each
  const int wn = (wv & 1) * 64;
  const int fr = lane & 15;        // fragment row (A) / col (B)
  const int kc = (lane >> 4) * 8;  // k-chunk base within BK

  const __bf16* srcAb0 = Xb + (size_t)(m0 + r0) * K_DIM + c0;
  const __bf16* srcAb1 = Xb + (size_t)(m0 + r1) * K_DIM + c1;
  const float* srcAf0 = X + (size_t)(m0 + r0) * K_DIM + c0;
  const float* srcAf1 = X + (size_t)(m0 + r1) * K_DIM + c1;
  const __bf16* srcBb0 = Wb + (size_t)(n0 + r0) * K_DIM + c0;
  const __bf16* srcBb1 = Wb + (size_t)(n0 + r1) * K_DIM + c1;
  const int* srcQ0 = Wq + (size_t)(n0 + r0) * K_DIM + c0;
  const int* srcQ1 = Wq + (size_t)(n0 + r1) * K_DIM + c1;

  for (int k0 = 0; k0 < K_DIM; k0 += BK) {
    if constexpr (MODE == 0) {
      gload_lds16(srcAb0 + k0, &As[e0]);
      gload_lds16(srcAb1 + k0, &As[e1]);
      gload_lds16(srcBb0 + k0, &Bs[e0]);
      gload_lds16(srcBb1 + k0, &Bs[e1]);
    } else {
      // A from fp32 via registers
      f32x4 a0 = *(const f32x4*)(srcAf0 + k0);
      f32x4 a1 = *(const f32x4*)(srcAf0 + k0 + 4);
      f32x4 a2 = *(const f32x4*)(srcAf1 + k0);
      f32x4 a3 = *(const f32x4*)(srcAf1 + k0 + 4);
      if constexpr (MODE == 1) {
        gload_lds16(srcBb0 + k0, &Bs[e0]);
        gload_lds16(srcBb1 + k0, &Bs[e1]);
      } else {
        i32x4 q0 = *(const i32x4*)(srcQ0 + k0);
        i32x4 q1 = *(const i32x4*)(srcQ0 + k0 + 4);
        i32x4 q2 = *(const i32x4*)(srcQ1 + k0);
        i32x4 q3 = *(const i32x4*)(srcQ1 + k0 + 4);
        *(bf16x8*)&Bs[e0] = cvt8i(q0, q1);
        *(bf16x8*)&Bs[e1] = cvt8i(q2, q3);
      }
      *(bf16x8*)&As[e0] = cvt8f(a0, a1);
      *(bf16x8*)&As[e1] = cvt8f(a2, a3);
    }
    __syncthreads();

    bf16x8 a[4], b[4];
#pragma unroll
    for (int m = 0; m < 4; ++m)
      a[m] = *(const bf16x8*)&As[(wm + m * 16 + fr) * BK + kc];
#pragma unroll
    for (int n = 0; n < 4; ++n)
      b[n] = *(const bf16x8*)&Bs[(wn + n * 16 + fr) * BK + kc];
#pragma unroll
    for (int m = 0; m < 4; ++m)
#pragma unroll
      for (int n = 0; n < 4; ++n)
        acc[m][n] =
            __builtin_amdgcn_mfma_f32_16x16x32_bf16(a[m], b[n], acc[m][n], 0, 0, 0);
    __syncthreads();
  }

  // C/D layout (m89-verified): col = lane&15, row = (lane>>4)*4 + reg
  const int cc = lane & 15;
  const int rr = (lane >> 4) * 4;
#pragma unroll
  for (int n = 0; n < 4; ++n) {
    const int col = n0 + wn + n * 16 + cc;
    const float sc = scale[col];
    const float bi = bias[col];
#pragma unroll
    for (int m = 0; m < 4; ++m) {
      const int rowb = m0 + wm + m * 16 + rr;
#pragma unroll
      for (int r = 0; r < 4; ++r) {
        out[(size_t)(rowb + r) * N_DIM + col] = acc[m][n][r] * sc + bi;
      }
    }
  }
}

extern "C" void kernel_launch(void* const* d_in, const int* in_sizes, int n_in,
                              void* d_out, int out_size, void* d_ws, size_t ws_size,
                              hipStream_t stream) {
  const float* X = (const float*)d_in[0];
  const int* Wq = (const int*)d_in[1];
  const float* scale = (const float*)d_in[2];
  const float* bias = (const float*)d_in[3];
  float* out = (float*)d_out;

  const size_t wbytes = (size_t)N_DIM * K_DIM * sizeof(__bf16);  // 90,177,536 (16B-aligned)
  const size_t xbytes = (size_t)M_DIM * K_DIM * sizeof(__bf16);  // 67,108,864
  const int nblocks = MT * NT;  // 5504
  const int n8w = (N_DIM * K_DIM) / 8;  // 5,636,096
  const int n8x = (M_DIM * K_DIM) / 8;  // 4,194,304

  if (ws_size >= wbytes + xbytes) {
    __bf16* Wb = (__bf16*)d_ws;
    __bf16* Xb = (__bf16*)((char*)d_ws + wbytes);
    wconv_kernel<<<dim3((n8w + 255) / 256), dim3(256), 0, stream>>>(Wq, Wb, n8w);
    xconv_kernel<<<dim3((n8x + 255) / 256), dim3(256), 0, stream>>>(X, Xb, n8x);
    gemm_kernel<0><<<dim3(nblocks), dim3(256), 0, stream>>>(
        X, Xb, Wb, Wq, scale, bias, out);
  } else if (ws_size >= wbytes) {
    __bf16* Wb = (__bf16*)d_ws;
    wconv_kernel<<<dim3((n8w + 255) / 256), dim3(256), 0, stream>>>(Wq, Wb, n8w);
    gemm_kernel<1><<<dim3(nblocks), dim3(256), 0, stream>>>(
        X, nullptr, Wb, Wq, scale, bias, out);
  } else {
    gemm_kernel<2><<<dim3(nblocks), dim3(256), 0, stream>>>(
        X, nullptr, nullptr, Wq, scale, bias, out);
  }
}

// Round 4
// 842.895 us; speedup vs baseline: 1.3244x; 1.3244x over previous
//
#include <hip/hip_runtime.h>
#include <hip/hip_bf16.h>
#include <stdint.h>

// Int8Linear: y[m,n] = scale[n] * sum_k x[m,k]*w[n,k] + bias[n]
// Device dtypes: x fp32 [8192,4096]; w int32 [11008,4096] (|v|<=127);
// scale/bias fp32 [11008]; out fp32 [8192,11008].
// Round 4: prepass (X,W -> bf16 in d_ws) + 256x256 deep-pipelined MFMA GEMM:
//   ring-of-4 LDS buffers (128 KiB), BK=32, 2 phases/K-tile, counted vmcnt(8)
//   (T3+T4), XOR bank-swizzle via pre-swizzled gload_lds source (T2),
//   setprio around MFMA clusters (T5), bijective XCD swizzle (T1).

#define K_DIM 4096
#define N_DIM 11008
#define M_DIM 8192

typedef __attribute__((ext_vector_type(8))) __bf16 bf16x8;
typedef __attribute__((ext_vector_type(4))) float f32x4;
typedef __attribute__((ext_vector_type(4))) int i32x4;

__device__ __forceinline__ void gload_lds16(const void* g, void* l) {
  __builtin_amdgcn_global_load_lds(
      (const __attribute__((address_space(1))) void*)g,
      (__attribute__((address_space(3))) void*)l, 16, 0, 0);
}

// ---------------- prepass conversions (validated round 3) ----------------

__global__ void __launch_bounds__(256) wconv_kernel(const int* __restrict__ w,
                                                    __bf16* __restrict__ o,
                                                    int n8) {
  int i = blockIdx.x * 256 + threadIdx.x;
  if (i >= n8) return;
  const i32x4* src = (const i32x4*)w;
  i32x4 v0 = src[2 * i];
  i32x4 v1 = src[2 * i + 1];
  bf16x8 r;
#pragma unroll
  for (int j = 0; j < 4; ++j) {
    r[j]     = (__bf16)(float)v0[j];
    r[j + 4] = (__bf16)(float)v1[j];
  }
  *((bf16x8*)o + i) = r;
}

__global__ void __launch_bounds__(256) xconv_kernel(const float* __restrict__ x,
                                                    __bf16* __restrict__ o,
                                                    int n8) {
  int i = blockIdx.x * 256 + threadIdx.x;
  if (i >= n8) return;
  const f32x4* src = (const f32x4*)x;
  f32x4 v0 = src[2 * i];
  f32x4 v1 = src[2 * i + 1];
  bf16x8 r;
#pragma unroll
  for (int j = 0; j < 4; ++j) {
    r[j]     = (__bf16)v0[j];
    r[j + 4] = (__bf16)v1[j];
  }
  *((bf16x8*)o + i) = r;
}

// ---------------- 256x256 deep-pipelined GEMM ----------------

#define BM 256
#define BN 256
#define BK 32
#define KT (K_DIM / BK)   /* 128 */
#define MT (M_DIM / BM)   /* 32 */
#define NT (N_DIM / BN)   /* 43 */
#define NBLK (MT * NT)    /* 1376 = 8*172 */
#define BUF_ELEMS (BM * BK * 2)  /* A+B = 16384 elems = 32 KiB */
#define BOFF (BM * BK)           /* 8192 */

__global__ void __launch_bounds__(512, 2) gemm256_kernel(
    const __bf16* __restrict__ Xb, const __bf16* __restrict__ Wb,
    const float* __restrict__ scale, const float* __restrict__ bias,
    float* __restrict__ out) {
  __shared__ __align__(16) __bf16 lds[4 * BUF_ELEMS];  // 128 KiB

  const int tid = threadIdx.x;
  const int lane = tid & 63;
  const int wv = tid >> 6;   // 0..7
  const int wr = wv >> 2;    // 0..1  (M half)
  const int wc = wv & 3;     // 0..3  (N quarter)

  // bijective XCD swizzle over 1376 = 8*172 blocks
  const int lid = blockIdx.x;
  const int swz = (lid & 7) * (NBLK / 8) + (lid >> 3);
  const int tm = swz / NT;
  const int tn = swz - tm * NT;
  const size_t m0 = (size_t)tm * BM;
  const size_t n0 = (size_t)tn * BN;

  // ---- staging addressing (T2: inverse-swizzled global source, linear LDS
  // dest; gload_lds writes wave-uniform base + lane*16) ----
  // one call: 8 waves x 1KB = 8KB = 128 rows of 64B; per operand 2 calls.
  // lane l covers row base+(l>>2), LDS 16B-slot (l&3); global slot must be
  // (l&3) ^ ((row>>1)&3) = (l&3) ^ ((l>>3)&3)  [base rows are mult. of 16].
  const int srow = wv * 16 + (lane >> 2);
  const int sslot8 = (((lane & 3) ^ ((lane >> 3) & 3)) << 3);
  const __bf16* gA0 = Xb + (m0 + srow) * K_DIM + sslot8;
  const __bf16* gA1 = gA0 + (size_t)128 * K_DIM;
  const __bf16* gB0 = Wb + (n0 + srow) * K_DIM + sslot8;
  const __bf16* gB1 = gB0 + (size_t)128 * K_DIM;
  const int lA0 = (wv * 16) * BK;           // wave-uniform LDS elem offsets
  const int lA1 = (128 + wv * 16) * BK;
  const int lB0 = BOFF + (wv * 16) * BK;
  const int lB1 = BOFF + (128 + wv * 16) * BK;

  // ---- fragment read addressing (swizzled): slot = kg ^ ((row>>1)&3) ----
  const int fr = lane & 15;
  const int kg = lane >> 4;
  const int sl8 = ((kg ^ ((fr >> 1) & 3)) << 3);
  const int aoffB = (wr * 128 + fr) * BK + sl8;
  const int boffB = BOFF + (wc * 64 + fr) * BK + sl8;

  f32x4 acc[8][4];
#pragma unroll
  for (int m = 0; m < 8; ++m)
#pragma unroll
    for (int n = 0; n < 4; ++n) acc[m][n] = (f32x4){0.f, 0.f, 0.f, 0.f};

  // ---- prologue: stage K-tiles 0,1,2 into buffers 0,1,2 ----
#pragma unroll
  for (int t = 0; t < 3; ++t) {
    __bf16* sb = &lds[t * BUF_ELEMS];
    const int ko = t * BK;
    gload_lds16(gA0 + ko, sb + lA0);
    gload_lds16(gA1 + ko, sb + lA1);
    gload_lds16(gB0 + ko, sb + lB0);
    gload_lds16(gB1 + ko, sb + lB1);
  }
  asm volatile("s_waitcnt vmcnt(8)" ::: "memory");  // tile 0 landed
  __builtin_amdgcn_sched_barrier(0);
  __builtin_amdgcn_s_barrier();

  for (int t = 0; t < KT; ++t) {
    const __bf16* buf = &lds[(t & 3) * BUF_ELEMS];
    const int ts = t + 3;
    __bf16* sb = &lds[(ts & 3) * BUF_ELEMS];
    const int ko = ts * BK;
    const bool do_stage = (ts < KT);

    // ================= phase 0: B-full + A[0..3] ; stage A(t+3) ==========
    bf16x8 bfr[4], afr[4];
#pragma unroll
    for (int nf = 0; nf < 4; ++nf)
      bfr[nf] = *(const bf16x8*)&buf[boffB + nf * (16 * BK)];
#pragma unroll
    for (int mf = 0; mf < 4; ++mf)
      afr[mf] = *(const bf16x8*)&buf[aoffB + mf * (16 * BK)];
    if (do_stage) {
      gload_lds16(gA0 + ko, sb + lA0);
      gload_lds16(gA1 + ko, sb + lA1);
    }
    __builtin_amdgcn_sched_barrier(0);
    __builtin_amdgcn_s_barrier();
    asm volatile("s_waitcnt lgkmcnt(0)" ::: "memory");
    __builtin_amdgcn_sched_barrier(0);
    __builtin_amdgcn_s_setprio(1);
#pragma unroll
    for (int mf = 0; mf < 4; ++mf)
#pragma unroll
      for (int nf = 0; nf < 4; ++nf)
        acc[mf][nf] = __builtin_amdgcn_mfma_f32_16x16x32_bf16(
            afr[mf], bfr[nf], acc[mf][nf], 0, 0, 0);
    __builtin_amdgcn_s_setprio(0);
    __builtin_amdgcn_sched_barrier(0);
    __builtin_amdgcn_s_barrier();

    // ================= phase 1: A[4..7] ; stage B(t+3) ; counted vmcnt ====
#pragma unroll
    for (int mf = 0; mf < 4; ++mf)
      afr[mf] = *(const bf16x8*)&buf[aoffB + (4 + mf) * (16 * BK)];
    if (do_stage) {
      gload_lds16(gB0 + ko, sb + lB0);
      gload_lds16(gB1 + ko, sb + lB1);
    }
    __builtin_amdgcn_sched_barrier(0);
    __builtin_amdgcn_s_barrier();
    asm volatile("s_waitcnt lgkmcnt(0)" ::: "memory");
    __builtin_amdgcn_sched_barrier(0);
    __builtin_amdgcn_s_setprio(1);
#pragma unroll
    for (int mf = 0; mf < 4; ++mf)
#pragma unroll
      for (int nf = 0; nf < 4; ++nf)
        acc[4 + mf][nf] = __builtin_amdgcn_mfma_f32_16x16x32_bf16(
            afr[mf], bfr[nf], acc[4 + mf][nf], 0, 0, 0);
    __builtin_amdgcn_s_setprio(0);
    // end-of-tile wait: guarantee tile t+1 fully landed before next reads.
    // steady state: 8 newest = tiles (t+2),(t+3) still in flight.
    if (t < KT - 3) {
      asm volatile("s_waitcnt vmcnt(8)" ::: "memory");
    } else if (t == KT - 3) {
      asm volatile("s_waitcnt vmcnt(4)" ::: "memory");
    } else {
      asm volatile("s_waitcnt vmcnt(0)" ::: "memory");
    }
    __builtin_amdgcn_sched_barrier(0);
    __builtin_amdgcn_s_barrier();
  }

  // ---- epilogue: C/D layout col=lane&15, row=(lane>>4)*4+reg ----
  const int cc = lane & 15;
  const int rr = (lane >> 4) * 4;
#pragma unroll
  for (int nf = 0; nf < 4; ++nf) {
    const int col = (int)n0 + wc * 64 + nf * 16 + cc;
    const float sc = scale[col];
    const float bi = bias[col];
#pragma unroll
    for (int mf = 0; mf < 8; ++mf) {
      const size_t rowb = m0 + wr * 128 + mf * 16 + rr;
#pragma unroll
      for (int r = 0; r < 4; ++r) {
        out[(rowb + r) * N_DIM + col] = acc[mf][nf][r] * sc + bi;
      }
    }
  }
}

// ---------------- fallback 128x128 kernel (round-3 validated) ----------------

#define FBM 128
#define FBN 128
#define FBK 32
#define FNT (N_DIM / FBN) /* 86 */
#define FMT (M_DIM / FBM) /* 64 */

__device__ __forceinline__ bf16x8 cvt8f(f32x4 a, f32x4 b) {
  bf16x8 h;
#pragma unroll
  for (int j = 0; j < 4; ++j) {
    h[j] = (__bf16)a[j];
    h[j + 4] = (__bf16)b[j];
  }
  return h;
}

__device__ __forceinline__ bf16x8 cvt8i(i32x4 a, i32x4 b) {
  bf16x8 h;
#pragma unroll
  for (int j = 0; j < 4; ++j) {
    h[j] = (__bf16)(float)a[j];
    h[j + 4] = (__bf16)(float)b[j];
  }
  return h;
}

template <int MODE>  // 1: W preconv; 2: no workspace
__global__ void __launch_bounds__(256, 2) gemm_fb_kernel(
    const float* __restrict__ X, const __bf16* __restrict__ Wb,
    const int* __restrict__ Wq, const float* __restrict__ scale,
    const float* __restrict__ bias, float* __restrict__ out) {
  __shared__ __align__(16) __bf16 As[FBM * FBK];
  __shared__ __align__(16) __bf16 Bs[FBN * FBK];

  const int tid = threadIdx.x;
  const int lane = tid & 63;
  const int wv = tid >> 6;

  const int lid = blockIdx.x;
  const int swz = (lid & 7) * ((FMT * FNT) >> 3) + (lid >> 3);
  const int tm = swz / FNT;
  const int tn = swz - tm * FNT;
  const int m0 = tm * FBM;
  const int n0 = tn * FBN;

  const int e0 = wv * 512 + lane * 8;
  const int e1 = e0 + 2048;
  const int r0 = e0 >> 5, c0 = e0 & 31;
  const int r1 = e1 >> 5, c1 = e1 & 31;

  f32x4 acc[4][4];
#pragma unroll
  for (int m = 0; m < 4; ++m)
#pragma unroll
    for (int n = 0; n < 4; ++n) acc[m][n] = (f32x4){0.f, 0.f, 0.f, 0.f};

  const int wm = (wv >> 1) * 64;
  const int wn = (wv & 1) * 64;
  const int fr = lane & 15;
  const int kc = (lane >> 4) * 8;

  const float* srcAf0 = X + (size_t)(m0 + r0) * K_DIM + c0;
  const float* srcAf1 = X + (size_t)(m0 + r1) * K_DIM + c1;
  const __bf16* srcBb0 = Wb + (size_t)(n0 + r0) * K_DIM + c0;
  const __bf16* srcBb1 = Wb + (size_t)(n0 + r1) * K_DIM + c1;
  const int* srcQ0 = Wq + (size_t)(n0 + r0) * K_DIM + c0;
  const int* srcQ1 = Wq + (size_t)(n0 + r1) * K_DIM + c1;

  for (int k0 = 0; k0 < K_DIM; k0 += FBK) {
    f32x4 a0 = *(const f32x4*)(srcAf0 + k0);
    f32x4 a1 = *(const f32x4*)(srcAf0 + k0 + 4);
    f32x4 a2 = *(const f32x4*)(srcAf1 + k0);
    f32x4 a3 = *(const f32x4*)(srcAf1 + k0 + 4);
    if constexpr (MODE == 1) {
      gload_lds16(srcBb0 + k0, &Bs[e0]);
      gload_lds16(srcBb1 + k0, &Bs[e1]);
    } else {
      i32x4 q0 = *(const i32x4*)(srcQ0 + k0);
      i32x4 q1 = *(const i32x4*)(srcQ0 + k0 + 4);
      i32x4 q2 = *(const i32x4*)(srcQ1 + k0);
      i32x4 q3 = *(const i32x4*)(srcQ1 + k0 + 4);
      *(bf16x8*)&Bs[e0] = cvt8i(q0, q1);
      *(bf16x8*)&Bs[e1] = cvt8i(q2, q3);
    }
    *(bf16x8*)&As[e0] = cvt8f(a0, a1);
    *(bf16x8*)&As[e1] = cvt8f(a2, a3);
    __syncthreads();

    bf16x8 a[4], b[4];
#pragma unroll
    for (int m = 0; m < 4; ++m)
      a[m] = *(const bf16x8*)&As[(wm + m * 16 + fr) * FBK + kc];
#pragma unroll
    for (int n = 0; n < 4; ++n)
      b[n] = *(const bf16x8*)&Bs[(wn + n * 16 + fr) * FBK + kc];
#pragma unroll
    for (int m = 0; m < 4; ++m)
#pragma unroll
      for (int n = 0; n < 4; ++n)
        acc[m][n] = __builtin_amdgcn_mfma_f32_16x16x32_bf16(a[m], b[n],
                                                            acc[m][n], 0, 0, 0);
    __syncthreads();
  }

  const int cc = lane & 15;
  const int rr = (lane >> 4) * 4;
#pragma unroll
  for (int n = 0; n < 4; ++n) {
    const int col = n0 + wn + n * 16 + cc;
    const float sc = scale[col];
    const float bi = bias[col];
#pragma unroll
    for (int m = 0; m < 4; ++m) {
      const int rowb = m0 + wm + m * 16 + rr;
#pragma unroll
      for (int r = 0; r < 4; ++r) {
        out[(size_t)(rowb + r) * N_DIM + col] = acc[m][n][r] * sc + bi;
      }
    }
  }
}

// ---------------- launch ----------------

extern "C" void kernel_launch(void* const* d_in, const int* in_sizes, int n_in,
                              void* d_out, int out_size, void* d_ws, size_t ws_size,
                              hipStream_t stream) {
  const float* X = (const float*)d_in[0];
  const int* Wq = (const int*)d_in[1];
  const float* scale = (const float*)d_in[2];
  const float* bias = (const float*)d_in[3];
  float* out = (float*)d_out;

  const size_t wbytes = (size_t)N_DIM * K_DIM * sizeof(__bf16);  // 90,177,536
  const size_t xbytes = (size_t)M_DIM * K_DIM * sizeof(__bf16);  // 67,108,864
  const int n8w = (N_DIM * K_DIM) / 8;
  const int n8x = (M_DIM * K_DIM) / 8;

  if (ws_size >= wbytes + xbytes) {
    __bf16* Wb = (__bf16*)d_ws;
    __bf16* Xb = (__bf16*)((char*)d_ws + wbytes);
    wconv_kernel<<<dim3((n8w + 255) / 256), dim3(256), 0, stream>>>(Wq, Wb, n8w);
    xconv_kernel<<<dim3((n8x + 255) / 256), dim3(256), 0, stream>>>(X, Xb, n8x);
    gemm256_kernel<<<dim3(NBLK), dim3(512), 0, stream>>>(Xb, Wb, scale, bias, out);
  } else if (ws_size >= wbytes) {
    __bf16* Wb = (__bf16*)d_ws;
    wconv_kernel<<<dim3((n8w + 255) / 256), dim3(256), 0, stream>>>(Wq, Wb, n8w);
    gemm_fb_kernel<1><<<dim3(FMT * FNT), dim3(256), 0, stream>>>(
        X, Wb, Wq, scale, bias, out);
  } else {
    gemm_fb_kernel<2><<<dim3(FMT * FNT), dim3(256), 0, stream>>>(
        X, nullptr, Wq, scale, bias, out);
  }
}

// Round 5
// 807.353 us; speedup vs baseline: 1.3827x; 1.0440x over previous
//
#include <hip/hip_runtime.h>
#include <hip/hip_bf16.h>
#include <stdint.h>

// Int8Linear: y[m,n] = scale[n] * sum_k x[m,k]*w[n,k] + bias[n]
// Device dtypes: x fp32 [8192,4096]; w int32 [11008,4096] (|v|<=127);
// scale/bias fp32 [11008]; out fp32 [8192,11008].
// Round 5: prepass (X,W -> bf16) + 256x256 GEMM with ring-of-4 LDS buffers
// and REGISTER-LEVEL ONE-PHASE-AHEAD pipelining: 4 sub-phases/K-tile, every
// MFMA cluster uses frags ds_read one phase earlier (LDS pipe overlaps matrix
// pipe). 2 barriers/tile (RAW vmcnt(6)+barrier, WAR tile-end barrier).
// T1 XCD swizzle, T2 LDS XOR-swizzle (round-4: 0 bank conflicts), T5 setprio.

#define K_DIM 4096
#define N_DIM 11008
#define M_DIM 8192

typedef __attribute__((ext_vector_type(8))) __bf16 bf16x8;
typedef __attribute__((ext_vector_type(4))) float f32x4;
typedef __attribute__((ext_vector_type(4))) int i32x4;

__device__ __forceinline__ void gload_lds16(const void* g, void* l) {
  __builtin_amdgcn_global_load_lds(
      (const __attribute__((address_space(1))) void*)g,
      (__attribute__((address_space(3))) void*)l, 16, 0, 0);
}

// ---------------- prepass conversions (validated round 3) ----------------

__global__ void __launch_bounds__(256) wconv_kernel(const int* __restrict__ w,
                                                    __bf16* __restrict__ o,
                                                    int n8) {
  int i = blockIdx.x * 256 + threadIdx.x;
  if (i >= n8) return;
  const i32x4* src = (const i32x4*)w;
  i32x4 v0 = src[2 * i];
  i32x4 v1 = src[2 * i + 1];
  bf16x8 r;
#pragma unroll
  for (int j = 0; j < 4; ++j) {
    r[j]     = (__bf16)(float)v0[j];
    r[j + 4] = (__bf16)(float)v1[j];
  }
  *((bf16x8*)o + i) = r;
}

__global__ void __launch_bounds__(256) xconv_kernel(const float* __restrict__ x,
                                                    __bf16* __restrict__ o,
                                                    int n8) {
  int i = blockIdx.x * 256 + threadIdx.x;
  if (i >= n8) return;
  const f32x4* src = (const f32x4*)x;
  f32x4 v0 = src[2 * i];
  f32x4 v1 = src[2 * i + 1];
  bf16x8 r;
#pragma unroll
  for (int j = 0; j < 4; ++j) {
    r[j]     = (__bf16)v0[j];
    r[j + 4] = (__bf16)v1[j];
  }
  *((bf16x8*)o + i) = r;
}

// ---------------- 256x256 pipelined GEMM ----------------

#define BM 256
#define BN 256
#define BK 32
#define KT (K_DIM / BK)   /* 128 */
#define MT (M_DIM / BM)   /* 32 */
#define NT (N_DIM / BN)   /* 43 */
#define NBLK (MT * NT)    /* 1376 = 8*172 */
#define BUF_ELEMS (BM * BK * 2)  /* A+B = 16384 elems = 32 KiB */
#define BOFF (BM * BK)           /* 8192 */

#define SB0 __builtin_amdgcn_sched_barrier(0)

__device__ __forceinline__ void mfma8(const bf16x8& a0, const bf16x8& a1,
                                      const bf16x8* b, f32x4* acc0,
                                      f32x4* acc1) {
  __builtin_amdgcn_s_setprio(1);
#pragma unroll
  for (int nf = 0; nf < 4; ++nf) {
    acc0[nf] =
        __builtin_amdgcn_mfma_f32_16x16x32_bf16(a0, b[nf], acc0[nf], 0, 0, 0);
    acc1[nf] =
        __builtin_amdgcn_mfma_f32_16x16x32_bf16(a1, b[nf], acc1[nf], 0, 0, 0);
  }
  __builtin_amdgcn_s_setprio(0);
}

__global__ void __launch_bounds__(512, 2) gemm256_kernel(
    const __bf16* __restrict__ Xb, const __bf16* __restrict__ Wb,
    const float* __restrict__ scale, const float* __restrict__ bias,
    float* __restrict__ out) {
  __shared__ __align__(16) __bf16 lds[4 * BUF_ELEMS];  // 128 KiB

  const int tid = threadIdx.x;
  const int lane = tid & 63;
  const int wv = tid >> 6;   // 0..7
  const int wr = wv >> 2;    // 0..1  (M half)
  const int wc = wv & 3;     // 0..3  (N quarter)

  // T1: bijective XCD swizzle over 1376 = 8*172 blocks
  const int lid = blockIdx.x;
  const int swz = (lid & 7) * (NBLK / 8) + (lid >> 3);
  const int tm = swz / NT;
  const int tn = swz - tm * NT;
  const size_t m0 = (size_t)tm * BM;
  const size_t n0 = (size_t)tn * BN;

  // T2 staging: inverse-swizzled global source, linear LDS dest.
  const int srow = wv * 16 + (lane >> 2);
  const int sslot8 = (((lane & 3) ^ ((lane >> 3) & 3)) << 3);
  const __bf16* gA0 = Xb + (m0 + srow) * K_DIM + sslot8;
  const __bf16* gA1 = gA0 + (size_t)128 * K_DIM;
  const __bf16* gB0 = Wb + (n0 + srow) * K_DIM + sslot8;
  const __bf16* gB1 = gB0 + (size_t)128 * K_DIM;
  const int lA0 = (wv * 16) * BK;
  const int lA1 = (128 + wv * 16) * BK;
  const int lB0 = BOFF + (wv * 16) * BK;
  const int lB1 = BOFF + (128 + wv * 16) * BK;

  // fragment read addressing (swizzled): slot = kg ^ ((row>>1)&3)
  const int fr = lane & 15;
  const int kg = lane >> 4;
  const int sl8 = ((kg ^ ((fr >> 1) & 3)) << 3);
  const int aoffB = (wr * 128 + fr) * BK + sl8;
  const int boffB = BOFF + (wc * 64 + fr) * BK + sl8;

#define RD_A(BUF, MF) (*(const bf16x8*)&(BUF)[aoffB + (MF) * (16 * BK)])
#define RD_B(BUF, NF) (*(const bf16x8*)&(BUF)[boffB + (NF) * (16 * BK)])

#define STAGE_A(TS)                                          \
  do {                                                       \
    if ((TS) < KT) {                                         \
      __bf16* stb = &lds[((TS) & 3) * BUF_ELEMS];            \
      const int ko = (TS) * BK;                              \
      gload_lds16(gA0 + ko, stb + lA0);                      \
      gload_lds16(gA1 + ko, stb + lA1);                      \
    }                                                        \
  } while (0)

#define STAGE_B(TS)                                          \
  do {                                                       \
    if ((TS) < KT) {                                         \
      __bf16* stb = &lds[((TS) & 3) * BUF_ELEMS];            \
      const int ko = (TS) * BK;                              \
      gload_lds16(gB0 + ko, stb + lB0);                      \
      gload_lds16(gB1 + ko, stb + lB1);                      \
    }                                                        \
  } while (0)

  f32x4 acc[8][4];
#pragma unroll
  for (int m = 0; m < 8; ++m)
#pragma unroll
    for (int n = 0; n < 4; ++n) acc[m][n] = (f32x4){0.f, 0.f, 0.f, 0.f};

  bf16x8 bX[4], bY[4], a01[2], a23[2], a45[2], a67[2];

  // ---- prologue: stage tiles 0,1,2 ----
#pragma unroll
  for (int t = 0; t < 3; ++t) {
    __bf16* sbp = &lds[t * BUF_ELEMS];
    const int ko = t * BK;
    gload_lds16(gA0 + ko, sbp + lA0);
    gload_lds16(gA1 + ko, sbp + lA1);
    gload_lds16(gB0 + ko, sbp + lB0);
    gload_lds16(gB1 + ko, sbp + lB1);
  }
  asm volatile("s_waitcnt vmcnt(8)" ::: "memory");  // tile 0 landed (own)
  SB0;
  __builtin_amdgcn_s_barrier();                     // tile 0 landed (all waves)
  // preload (acts as P3(-1)): bfr(t0) + a01(t0)
  bX[0] = RD_B(lds, 0); bX[1] = RD_B(lds, 1);
  bX[2] = RD_B(lds, 2); bX[3] = RD_B(lds, 3);
  a01[0] = RD_A(lds, 0); a01[1] = RD_A(lds, 1);

  // tile body: P0..P3; MFMA always uses frags read one phase earlier.
#define TILE_BODY(BCUR, BNXT, T)                                           \
  do {                                                                     \
    const __bf16* buf = &lds[((T) & 3) * BUF_ELEMS];                       \
    /* P0: stage A(T+3); read a23; MFMA a01 */                             \
    STAGE_A((T) + 3);                                                      \
    a23[0] = RD_A(buf, 2); a23[1] = RD_A(buf, 3);                          \
    SB0;                                                                   \
    mfma8(a01[0], a01[1], BCUR, acc[0], acc[1]);                           \
    SB0;                                                                   \
    /* P1: read a45; MFMA a23 */                                           \
    a45[0] = RD_A(buf, 4); a45[1] = RD_A(buf, 5);                          \
    SB0;                                                                   \
    mfma8(a23[0], a23[1], BCUR, acc[2], acc[3]);                           \
    SB0;                                                                   \
    /* P2: read a67; MFMA a45 */                                           \
    a67[0] = RD_A(buf, 6); a67[1] = RD_A(buf, 7);                          \
    SB0;                                                                   \
    mfma8(a45[0], a45[1], BCUR, acc[4], acc[5]);                           \
    SB0;                                                                   \
    /* P3: fence tile T+1; read bfr(T+1)+a01(T+1); stage B(T+3); MFMA a67 */ \
    if ((T) < KT - 1) {                                                    \
      if ((T) < KT - 3)                                                    \
        asm volatile("s_waitcnt vmcnt(6)" ::: "memory");                   \
      else if ((T) == KT - 3)                                              \
        asm volatile("s_waitcnt vmcnt(4)" ::: "memory");                   \
      else                                                                 \
        asm volatile("s_waitcnt vmcnt(0)" ::: "memory");                   \
      SB0;                                                                 \
      __builtin_amdgcn_s_barrier(); /* RAW: all waves staged T+1 */        \
      const __bf16* nbuf = &lds[(((T) + 1) & 3) * BUF_ELEMS];              \
      BNXT[0] = RD_B(nbuf, 0); BNXT[1] = RD_B(nbuf, 1);                    \
      BNXT[2] = RD_B(nbuf, 2); BNXT[3] = RD_B(nbuf, 3);                    \
      a01[0] = RD_A(nbuf, 0); a01[1] = RD_A(nbuf, 1);                      \
      STAGE_B((T) + 3);                                                    \
    }                                                                      \
    SB0;                                                                   \
    mfma8(a67[0], a67[1], BCUR, acc[6], acc[7]);                           \
    SB0;                                                                   \
    if ((T) < KT - 1) __builtin_amdgcn_s_barrier(); /* WAR tile-end */     \
  } while (0)

  for (int t = 0; t < KT; t += 2) {
    TILE_BODY(bX, bY, t);
    TILE_BODY(bY, bX, t + 1);
  }

  // ---- epilogue: C/D layout col=lane&15, row=(lane>>4)*4+reg ----
  const int cc = lane & 15;
  const int rr = (lane >> 4) * 4;
#pragma unroll
  for (int nf = 0; nf < 4; ++nf) {
    const int col = (int)n0 + wc * 64 + nf * 16 + cc;
    const float sc = scale[col];
    const float bi = bias[col];
#pragma unroll
    for (int mf = 0; mf < 8; ++mf) {
      const size_t rowb = m0 + wr * 128 + mf * 16 + rr;
#pragma unroll
      for (int r = 0; r < 4; ++r) {
        out[(rowb + r) * N_DIM + col] = acc[mf][nf][r] * sc + bi;
      }
    }
  }
#undef TILE_BODY
#undef STAGE_A
#undef STAGE_B
#undef RD_A
#undef RD_B
}

// ---------------- fallback 128x128 kernel (round-3 validated) ----------------

#define FBM 128
#define FBN 128
#define FBK 32
#define FNT (N_DIM / FBN) /* 86 */
#define FMT (M_DIM / FBM) /* 64 */

__device__ __forceinline__ bf16x8 cvt8f(f32x4 a, f32x4 b) {
  bf16x8 h;
#pragma unroll
  for (int j = 0; j < 4; ++j) {
    h[j] = (__bf16)a[j];
    h[j + 4] = (__bf16)b[j];
  }
  return h;
}

__device__ __forceinline__ bf16x8 cvt8i(i32x4 a, i32x4 b) {
  bf16x8 h;
#pragma unroll
  for (int j = 0; j < 4; ++j) {
    h[j] = (__bf16)(float)a[j];
    h[j + 4] = (__bf16)(float)b[j];
  }
  return h;
}

template <int MODE>  // 1: W preconv; 2: no workspace
__global__ void __launch_bounds__(256, 2) gemm_fb_kernel(
    const float* __restrict__ X, const __bf16* __restrict__ Wb,
    const int* __restrict__ Wq, const float* __restrict__ scale,
    const float* __restrict__ bias, float* __restrict__ out) {
  __shared__ __align__(16) __bf16 As[FBM * FBK];
  __shared__ __align__(16) __bf16 Bs[FBN * FBK];

  const int tid = threadIdx.x;
  const int lane = tid & 63;
  const int wv = tid >> 6;

  const int lid = blockIdx.x;
  const int swz = (lid & 7) * ((FMT * FNT) >> 3) + (lid >> 3);
  const int tm = swz / FNT;
  const int tn = swz - tm * FNT;
  const int m0 = tm * FBM;
  const int n0 = tn * FBN;

  const int e0 = wv * 512 + lane * 8;
  const int e1 = e0 + 2048;
  const int r0 = e0 >> 5, c0 = e0 & 31;
  const int r1 = e1 >> 5, c1 = e1 & 31;

  f32x4 acc[4][4];
#pragma unroll
  for (int m = 0; m < 4; ++m)
#pragma unroll
    for (int n = 0; n < 4; ++n) acc[m][n] = (f32x4){0.f, 0.f, 0.f, 0.f};

  const int wm = (wv >> 1) * 64;
  const int wn = (wv & 1) * 64;
  const int fr = lane & 15;
  const int kc = (lane >> 4) * 8;

  const float* srcAf0 = X + (size_t)(m0 + r0) * K_DIM + c0;
  const float* srcAf1 = X + (size_t)(m0 + r1) * K_DIM + c1;
  const __bf16* srcBb0 = Wb + (size_t)(n0 + r0) * K_DIM + c0;
  const __bf16* srcBb1 = Wb + (size_t)(n0 + r1) * K_DIM + c1;
  const int* srcQ0 = Wq + (size_t)(n0 + r0) * K_DIM + c0;
  const int* srcQ1 = Wq + (size_t)(n0 + r1) * K_DIM + c1;

  for (int k0 = 0; k0 < K_DIM; k0 += FBK) {
    f32x4 a0 = *(const f32x4*)(srcAf0 + k0);
    f32x4 a1 = *(const f32x4*)(srcAf0 + k0 + 4);
    f32x4 a2 = *(const f32x4*)(srcAf1 + k0);
    f32x4 a3 = *(const f32x4*)(srcAf1 + k0 + 4);
    if constexpr (MODE == 1) {
      gload_lds16(srcBb0 + k0, &Bs[e0]);
      gload_lds16(srcBb1 + k0, &Bs[e1]);
    } else {
      i32x4 q0 = *(const i32x4*)(srcQ0 + k0);
      i32x4 q1 = *(const i32x4*)(srcQ0 + k0 + 4);
      i32x4 q2 = *(const i32x4*)(srcQ1 + k0);
      i32x4 q3 = *(const i32x4*)(srcQ1 + k0 + 4);
      *(bf16x8*)&Bs[e0] = cvt8i(q0, q1);
      *(bf16x8*)&Bs[e1] = cvt8i(q2, q3);
    }
    *(bf16x8*)&As[e0] = cvt8f(a0, a1);
    *(bf16x8*)&As[e1] = cvt8f(a2, a3);
    __syncthreads();

    bf16x8 a[4], b[4];
#pragma unroll
    for (int m = 0; m < 4; ++m)
      a[m] = *(const bf16x8*)&As[(wm + m * 16 + fr) * FBK + kc];
#pragma unroll
    for (int n = 0; n < 4; ++n)
      b[n] = *(const bf16x8*)&Bs[(wn + n * 16 + fr) * FBK + kc];
#pragma unroll
    for (int m = 0; m < 4; ++m)
#pragma unroll
      for (int n = 0; n < 4; ++n)
        acc[m][n] = __builtin_amdgcn_mfma_f32_16x16x32_bf16(a[m], b[n],
                                                            acc[m][n], 0, 0, 0);
    __syncthreads();
  }

  const int cc = lane & 15;
  const int rr = (lane >> 4) * 4;
#pragma unroll
  for (int n = 0; n < 4; ++n) {
    const int col = n0 + wn + n * 16 + cc;
    const float sc = scale[col];
    const float bi = bias[col];
#pragma unroll
    for (int m = 0; m < 4; ++m) {
      const int rowb = m0 + wm + m * 16 + rr;
#pragma unroll
      for (int r = 0; r < 4; ++r) {
        out[(size_t)(rowb + r) * N_DIM + col] = acc[m][n][r] * sc + bi;
      }
    }
  }
}

// ---------------- launch ----------------

extern "C" void kernel_launch(void* const* d_in, const int* in_sizes, int n_in,
                              void* d_out, int out_size, void* d_ws, size_t ws_size,
                              hipStream_t stream) {
  const float* X = (const float*)d_in[0];
  const int* Wq = (const int*)d_in[1];
  const float* scale = (const float*)d_in[2];
  const float* bias = (const float*)d_in[3];
  float* out = (float*)d_out;

  const size_t wbytes = (size_t)N_DIM * K_DIM * sizeof(__bf16);  // 90,177,536
  const size_t xbytes = (size_t)M_DIM * K_DIM * sizeof(__bf16);  // 67,108,864
  const int n8w = (N_DIM * K_DIM) / 8;
  const int n8x = (M_DIM * K_DIM) / 8;

  if (ws_size >= wbytes + xbytes) {
    __bf16* Wb = (__bf16*)d_ws;
    __bf16* Xb = (__bf16*)((char*)d_ws + wbytes);
    wconv_kernel<<<dim3((n8w + 255) / 256), dim3(256), 0, stream>>>(Wq, Wb, n8w);
    xconv_kernel<<<dim3((n8x + 255) / 256), dim3(256), 0, stream>>>(X, Xb, n8x);
    gemm256_kernel<<<dim3(NBLK), dim3(512), 0, stream>>>(Xb, Wb, scale, bias, out);
  } else if (ws_size >= wbytes) {
    __bf16* Wb = (__bf16*)d_ws;
    wconv_kernel<<<dim3((n8w + 255) / 256), dim3(256), 0, stream>>>(Wq, Wb, n8w);
    gemm_fb_kernel<1><<<dim3(FMT * FNT), dim3(256), 0, stream>>>(
        X, Wb, Wq, scale, bias, out);
  } else {
    gemm_fb_kernel<2><<<dim3(FMT * FNT), dim3(256), 0, stream>>>(
        X, nullptr, Wq, scale, bias, out);
  }
}

// Round 7
// 738.618 us; speedup vs baseline: 1.5114x; 1.0931x over previous
//
#include <hip/hip_runtime.h>
#include <hip/hip_bf16.h>
#include <stdint.h>

// Int8Linear: y[m,n] = scale[n] * sum_k x[m,k]*w[n,k] + bias[n]
// Device dtypes: x fp32 [8192,4096]; w int32 [11008,4096] (|v|<=127);
// scale/bias fp32 [11008]; out fp32 [8192,11008].
// Round 7: round-6 m201-template with the staging K-offset BUG FIXED (r6
// staged k=[0,64) for every tile -> absmax 2058 = 64x first-chunk product).
// 256x256 GEMM, BK=64, dbuf-2 LDS (128 KiB), 4 phases/K-tile, counted
// vmcnt(4) stagger, 8-slot XOR bank swizzle, bijective XCD swizzle.

#define K_DIM 4096
#define N_DIM 11008
#define M_DIM 8192

typedef __attribute__((ext_vector_type(8))) __bf16 bf16x8;
typedef __attribute__((ext_vector_type(4))) float f32x4;
typedef __attribute__((ext_vector_type(4))) int i32x4;

#define SB0 __builtin_amdgcn_sched_barrier(0)

__device__ __forceinline__ void gload_lds16(const void* g, void* l) {
  __builtin_amdgcn_global_load_lds(
      (const __attribute__((address_space(1))) void*)g,
      (__attribute__((address_space(3))) void*)l, 16, 0, 0);
}

// ---------------- prepass conversions (validated round 3) ----------------

__global__ void __launch_bounds__(256) wconv_kernel(const int* __restrict__ w,
                                                    __bf16* __restrict__ o,
                                                    int n8) {
  int i = blockIdx.x * 256 + threadIdx.x;
  if (i >= n8) return;
  const i32x4* src = (const i32x4*)w;
  i32x4 v0 = src[2 * i];
  i32x4 v1 = src[2 * i + 1];
  bf16x8 r;
#pragma unroll
  for (int j = 0; j < 4; ++j) {
    r[j]     = (__bf16)(float)v0[j];
    r[j + 4] = (__bf16)(float)v1[j];
  }
  *((bf16x8*)o + i) = r;
}

__global__ void __launch_bounds__(256) xconv_kernel(const float* __restrict__ x,
                                                    __bf16* __restrict__ o,
                                                    int n8) {
  int i = blockIdx.x * 256 + threadIdx.x;
  if (i >= n8) return;
  const f32x4* src = (const f32x4*)x;
  f32x4 v0 = src[2 * i];
  f32x4 v1 = src[2 * i + 1];
  bf16x8 r;
#pragma unroll
  for (int j = 0; j < 4; ++j) {
    r[j]     = (__bf16)v0[j];
    r[j + 4] = (__bf16)v1[j];
  }
  *((bf16x8*)o + i) = r;
}

// ---------------- 256x256 BK=64 4-phase GEMM ----------------

#define BM 256
#define BN 256
#define BK 64
#define KT (K_DIM / BK)  /* 64 */
#define MT (M_DIM / BM)  /* 32 */
#define NT (N_DIM / BN)  /* 43 */
#define NBLK (MT * NT)   /* 1376 = 8*172 */
#define ABUF 16384       /* elems: one operand tile 256x64 */
#define BUFSZ 32768      /* elems: A+B per buffer = 64 KiB */

template <int RH, int CH>
__device__ __forceinline__ void mfma_quad(const bf16x8 aF[8],
                                          const bf16x8 bF[4],
                                          f32x4 acc[8][4]) {
  __builtin_amdgcn_s_setprio(1);
#pragma unroll
  for (int mf = 0; mf < 4; ++mf)
#pragma unroll
    for (int nf = 0; nf < 2; ++nf)
#pragma unroll
      for (int ks = 0; ks < 2; ++ks)
        acc[RH * 4 + mf][CH * 2 + nf] = __builtin_amdgcn_mfma_f32_16x16x32_bf16(
            aF[mf * 2 + ks], bF[nf * 2 + ks], acc[RH * 4 + mf][CH * 2 + nf], 0,
            0, 0);
  __builtin_amdgcn_s_setprio(0);
}

__global__ void __launch_bounds__(512, 2) gemm256_kernel(
    const __bf16* __restrict__ Xb, const __bf16* __restrict__ Wb,
    const float* __restrict__ scale, const float* __restrict__ bias,
    float* __restrict__ out) {
  __shared__ __align__(16) __bf16 lds[2 * BUFSZ];  // 128 KiB

  const int tid = threadIdx.x;
  const int lane = tid & 63;
  const int wv = tid >> 6;  // 0..7
  const int wr = wv >> 2;   // 0..1 (M half: 128 rows)
  const int wc = wv & 3;    // 0..3 (N quarter: 64 cols)

  // T1: bijective XCD swizzle (1376 = 8*172)
  const int lid = blockIdx.x;
  const int swz = (lid & 7) * (NBLK / 8) + (lid >> 3);
  const int tm = swz / NT;
  const int tn = swz - tm * NT;
  const size_t m0 = (size_t)tm * BM;
  const size_t n0 = (size_t)tn * BN;

  // ---- staging addressing: per call, wave wv covers rows [R0+wv*8, R0+wv*8+8),
  // 8 slots of 16B per row. LDS[R][s] holds global k-chunk (s ^ (R&7)):
  // inverse-swizzled per-lane GLOBAL source + wave-uniform LDS base (hardware
  // writes lane i at base + i*16B).
  const int srow = tid >> 3;                    // 0..63 (= wv*8 + (lane>>3))
  const int gchunk = (tid & 7) ^ (srow & 7);
  const size_t gOff = (size_t)srow * K_DIM + gchunk * 8;
  const int ldsWv = wv * 512;                   // wave-uniform elem offset
  const __bf16* GA = Xb + m0 * K_DIM;
  const __bf16* GB = Wb + n0 * K_DIM;

#define STG(LP, OPB, R0, G, TS)                                        \
  gload_lds16((G) + (size_t)(R0) * K_DIM + (size_t)(TS) * BK + gOff,   \
              &lds[(LP) * BUFSZ + (OPB) + (R0) * 64 + ldsWv])

  // ---- fragment read addressing (swizzled): slot = (ks*4+kg) ^ (fr&7) ----
  const int fr = lane & 15;
  const int kg = lane >> 4;
  const int sw = fr & 7;
  const int aBase = (wr * 128 + fr) * 64;
  const int bBase = ABUF + (wc * 64 + fr) * 64;
  const int s0 = ((0 * 4 + kg) ^ sw) * 8;
  const int s1 = ((1 * 4 + kg) ^ sw) * 8;

#define RDA(LP, RF, KS) \
  (*(const bf16x8*)&lds[(LP)*BUFSZ + aBase + (RF)*1024 + ((KS) ? s1 : s0)])
#define RDB(LP, CF, KS) \
  (*(const bf16x8*)&lds[(LP)*BUFSZ + bBase + (CF)*1024 + ((KS) ? s1 : s0)])

  f32x4 acc[8][4];
#pragma unroll
  for (int m = 0; m < 8; ++m)
#pragma unroll
    for (int n = 0; n < 4; ++n) acc[m][n] = (f32x4){0.f, 0.f, 0.f, 0.f};

  // ---- prologue: steady-state staging queue, oldest -> newest:
  // B(0) x4, A(0) x4, B(1) x4; fence leaves B(1) in flight.
  STG(0, ABUF, 0, GB, 0);   STG(0, ABUF, 64, GB, 0);
  STG(0, ABUF, 128, GB, 0); STG(0, ABUF, 192, GB, 0);
  STG(0, 0, 0, GA, 0);      STG(0, 0, 64, GA, 0);
  STG(0, 0, 128, GA, 0);    STG(0, 0, 192, GA, 0);
  STG(1, ABUF, 0, GB, 1);   STG(1, ABUF, 64, GB, 1);
  STG(1, ABUF, 128, GB, 1); STG(1, ABUF, 192, GB, 1);
  asm volatile("s_waitcnt vmcnt(4)" ::: "memory");
  SB0;
  __builtin_amdgcn_s_barrier();

  bf16x8 aF[8], bA[4], bB[4];

  for (int t = 0; t < KT; ++t) {
    const int p = t & 1;
    const int np = p ^ 1;
    const bool stA = (t + 1 < KT);  // stage A(t+1) into np
    const bool stB = (t + 2 < KT);  // stage B(t+2) into p (B(t) dead by P1-end)

    // ====== P0: read A-rh0 (8) + B-ch0 (4); stage Ah0(t+1); MFMA q(0,0) ===
#pragma unroll
    for (int rf = 0; rf < 4; ++rf) {
      aF[rf * 2] = RDA(p, rf, 0);
      aF[rf * 2 + 1] = RDA(p, rf, 1);
    }
#pragma unroll
    for (int cf = 0; cf < 2; ++cf) {
      bA[cf * 2] = RDB(p, cf, 0);
      bA[cf * 2 + 1] = RDB(p, cf, 1);
    }
    if (stA) { STG(np, 0, 0, GA, t + 1); STG(np, 0, 64, GA, t + 1); }
    asm volatile("s_waitcnt lgkmcnt(8)" ::: "memory");
    SB0;
    __builtin_amdgcn_s_barrier();
    asm volatile("s_waitcnt lgkmcnt(0)" ::: "memory");
    SB0;
    mfma_quad<0, 0>(aF, bA, acc);
    SB0;
    __builtin_amdgcn_s_barrier();

    // ====== P1: read B-ch1 (4); stage Ah1(t+1); MFMA q(0,1) ===============
#pragma unroll
    for (int cf = 0; cf < 2; ++cf) {
      bB[cf * 2] = RDB(p, 2 + cf, 0);
      bB[cf * 2 + 1] = RDB(p, 2 + cf, 1);
    }
    if (stA) { STG(np, 0, 128, GA, t + 1); STG(np, 0, 192, GA, t + 1); }
    SB0;
    __builtin_amdgcn_s_barrier();
    asm volatile("s_waitcnt lgkmcnt(0)" ::: "memory");
    SB0;
    mfma_quad<0, 1>(aF, bB, acc);
    SB0;
    __builtin_amdgcn_s_barrier();

    // ====== P2: read A-rh1 (8); stage Bh0(t+2); MFMA q(1,1) ===============
#pragma unroll
    for (int rf = 0; rf < 4; ++rf) {
      aF[rf * 2] = RDA(p, 4 + rf, 0);
      aF[rf * 2 + 1] = RDA(p, 4 + rf, 1);
    }
    if (stB) { STG(p, ABUF, 0, GB, t + 2); STG(p, ABUF, 64, GB, t + 2); }
    SB0;
    __builtin_amdgcn_s_barrier();
    asm volatile("s_waitcnt lgkmcnt(0)" ::: "memory");
    SB0;
    mfma_quad<1, 1>(aF, bB, acc);
    SB0;
    __builtin_amdgcn_s_barrier();

    // ====== P3: stage Bh1(t+2); MFMA q(1,0); counted fence; barrier =======
    if (stB) { STG(p, ABUF, 128, GB, t + 2); STG(p, ABUF, 192, GB, t + 2); }
    SB0;
    mfma_quad<1, 0>(aF, bA, acc);
    SB0;
    // fence: all of tile t+1 landed; newest-4 in flight = B(t+2).
    if (stB)
      asm volatile("s_waitcnt vmcnt(4)" ::: "memory");
    else
      asm volatile("s_waitcnt vmcnt(0)" ::: "memory");
    SB0;
    __builtin_amdgcn_s_barrier();
  }

  // ---- epilogue: C/D layout col=lane&15, row=(lane>>4)*4+reg ----
  const int cc = lane & 15;
  const int rr = (lane >> 4) * 4;
#pragma unroll
  for (int nf = 0; nf < 4; ++nf) {
    const int col = (int)n0 + wc * 64 + nf * 16 + cc;
    const float sc = scale[col];
    const float bi = bias[col];
#pragma unroll
    for (int mf = 0; mf < 8; ++mf) {
      const size_t rowb = m0 + wr * 128 + mf * 16 + rr;
#pragma unroll
      for (int r = 0; r < 4; ++r) {
        out[(rowb + r) * N_DIM + col] = acc[mf][nf][r] * sc + bi;
      }
    }
  }
#undef STG
#undef RDA
#undef RDB
}

// ---------------- fallback 128x128 kernel (round-3 validated) ----------------

#define FBM 128
#define FBN 128
#define FBK 32
#define FNT (N_DIM / FBN) /* 86 */
#define FMT (M_DIM / FBM) /* 64 */

__device__ __forceinline__ bf16x8 cvt8f(f32x4 a, f32x4 b) {
  bf16x8 h;
#pragma unroll
  for (int j = 0; j < 4; ++j) {
    h[j] = (__bf16)a[j];
    h[j + 4] = (__bf16)b[j];
  }
  return h;
}

__device__ __forceinline__ bf16x8 cvt8i(i32x4 a, i32x4 b) {
  bf16x8 h;
#pragma unroll
  for (int j = 0; j < 4; ++j) {
    h[j] = (__bf16)(float)a[j];
    h[j + 4] = (__bf16)(float)b[j];
  }
  return h;
}

template <int MODE>  // 1: W preconv; 2: no workspace
__global__ void __launch_bounds__(256, 2) gemm_fb_kernel(
    const float* __restrict__ X, const __bf16* __restrict__ Wb,
    const int* __restrict__ Wq, const float* __restrict__ scale,
    const float* __restrict__ bias, float* __restrict__ out) {
  __shared__ __align__(16) __bf16 As[FBM * FBK];
  __shared__ __align__(16) __bf16 Bs[FBN * FBK];

  const int tid = threadIdx.x;
  const int lane = tid & 63;
  const int wv = tid >> 6;

  const int lid = blockIdx.x;
  const int swz = (lid & 7) * ((FMT * FNT) >> 3) + (lid >> 3);
  const int tm = swz / FNT;
  const int tn = swz - tm * FNT;
  const int m0 = tm * FBM;
  const int n0 = tn * FBN;

  const int e0 = wv * 512 + lane * 8;
  const int e1 = e0 + 2048;
  const int r0 = e0 >> 5, c0 = e0 & 31;
  const int r1 = e1 >> 5, c1 = e1 & 31;

  f32x4 acc[4][4];
#pragma unroll
  for (int m = 0; m < 4; ++m)
#pragma unroll
    for (int n = 0; n < 4; ++n) acc[m][n] = (f32x4){0.f, 0.f, 0.f, 0.f};

  const int wm = (wv >> 1) * 64;
  const int wn = (wv & 1) * 64;
  const int fr = lane & 15;
  const int kc = (lane >> 4) * 8;

  const float* srcAf0 = X + (size_t)(m0 + r0) * K_DIM + c0;
  const float* srcAf1 = X + (size_t)(m0 + r1) * K_DIM + c1;
  const __bf16* srcBb0 = Wb + (size_t)(n0 + r0) * K_DIM + c0;
  const __bf16* srcBb1 = Wb + (size_t)(n0 + r1) * K_DIM + c1;
  const int* srcQ0 = Wq + (size_t)(n0 + r0) * K_DIM + c0;
  const int* srcQ1 = Wq + (size_t)(n0 + r1) * K_DIM + c1;

  for (int k0 = 0; k0 < K_DIM; k0 += FBK) {
    f32x4 a0 = *(const f32x4*)(srcAf0 + k0);
    f32x4 a1 = *(const f32x4*)(srcAf0 + k0 + 4);
    f32x4 a2 = *(const f32x4*)(srcAf1 + k0);
    f32x4 a3 = *(const f32x4*)(srcAf1 + k0 + 4);
    if constexpr (MODE == 1) {
      gload_lds16(srcBb0 + k0, &Bs[e0]);
      gload_lds16(srcBb1 + k0, &Bs[e1]);
    } else {
      i32x4 q0 = *(const i32x4*)(srcQ0 + k0);
      i32x4 q1 = *(const i32x4*)(srcQ0 + k0 + 4);
      i32x4 q2 = *(const i32x4*)(srcQ1 + k0);
      i32x4 q3 = *(const i32x4*)(srcQ1 + k0 + 4);
      *(bf16x8*)&Bs[e0] = cvt8i(q0, q1);
      *(bf16x8*)&Bs[e1] = cvt8i(q2, q3);
    }
    *(bf16x8*)&As[e0] = cvt8f(a0, a1);
    *(bf16x8*)&As[e1] = cvt8f(a2, a3);
    __syncthreads();

    bf16x8 a[4], b[4];
#pragma unroll
    for (int m = 0; m < 4; ++m)
      a[m] = *(const bf16x8*)&As[(wm + m * 16 + fr) * FBK + kc];
#pragma unroll
    for (int n = 0; n < 4; ++n)
      b[n] = *(const bf16x8*)&Bs[(wn + n * 16 + fr) * FBK + kc];
#pragma unroll
    for (int m = 0; m < 4; ++m)
#pragma unroll
      for (int n = 0; n < 4; ++n)
        acc[m][n] = __builtin_amdgcn_mfma_f32_16x16x32_bf16(a[m], b[n],
                                                            acc[m][n], 0, 0, 0);
    __syncthreads();
  }

  const int cc = lane & 15;
  const int rr = (lane >> 4) * 4;
#pragma unroll
  for (int n = 0; n < 4; ++n) {
    const int col = n0 + wn + n * 16 + cc;
    const float sc = scale[col];
    const float bi = bias[col];
#pragma unroll
    for (int m = 0; m < 4; ++m) {
      const int rowb = m0 + wm + m * 16 + rr;
#pragma unroll
      for (int r = 0; r < 4; ++r) {
        out[(size_t)(rowb + r) * N_DIM + col] = acc[m][n][r] * sc + bi;
      }
    }
  }
}

// ---------------- launch ----------------

extern "C" void kernel_launch(void* const* d_in, const int* in_sizes, int n_in,
                              void* d_out, int out_size, void* d_ws, size_t ws_size,
                              hipStream_t stream) {
  const float* X = (const float*)d_in[0];
  const int* Wq = (const int*)d_in[1];
  const float* scale = (const float*)d_in[2];
  const float* bias = (const float*)d_in[3];
  float* out = (float*)d_out;

  const size_t wbytes = (size_t)N_DIM * K_DIM * sizeof(__bf16);  // 90,177,536
  const size_t xbytes = (size_t)M_DIM * K_DIM * sizeof(__bf16);  // 67,108,864
  const int n8w = (N_DIM * K_DIM) / 8;
  const int n8x = (M_DIM * K_DIM) / 8;

  if (ws_size >= wbytes + xbytes) {
    __bf16* Wb = (__bf16*)d_ws;
    __bf16* Xb = (__bf16*)((char*)d_ws + wbytes);
    wconv_kernel<<<dim3((n8w + 255) / 256), dim3(256), 0, stream>>>(Wq, Wb, n8w);
    xconv_kernel<<<dim3((n8x + 255) / 256), dim3(256), 0, stream>>>(X, Xb, n8x);
    gemm256_kernel<<<dim3(NBLK), dim3(512), 0, stream>>>(Xb, Wb, scale, bias, out);
  } else if (ws_size >= wbytes) {
    __bf16* Wb = (__bf16*)d_ws;
    wconv_kernel<<<dim3((n8w + 255) / 256), dim3(256), 0, stream>>>(Wq, Wb, n8w);
    gemm_fb_kernel<1><<<dim3(FMT * FNT), dim3(256), 0, stream>>>(
        X, Wb, Wq, scale, bias, out);
  } else {
    gemm_fb_kernel<2><<<dim3(FMT * FNT), dim3(256), 0, stream>>>(
        X, nullptr, Wq, scale, bias, out);
  }
}